// Round 9
// baseline (676.169 us; speedup 1.0000x reference)
//
#include <hip/hip_runtime.h>

// MultiGNN: B=256, A=64 -> 16384 images of 8x15x15
// convs: 8->16 (15->13), 16->32 (13->11), 32->16 (11->9), 16->32 (9->7)
// flatten 32*7*7=1568 -> MLP 128,128,128 -> GCN over 64 agents, E=128
//
// R9: (a) full MFMA pipeline — conv (R8, 317us) PLUS the MLP chain as
// split-bf16 MFMA GEMMs (was ~335us of scalar fp32 vector GEMM). Conv L3
// emits X0 as bf16 hi/lo planes; wprep_mlp packs MLP/GCN weights into
// B-fragment order; mgemm does 24 MFMA/chunk/wave (hh+lh+hl). gcn_agg
// stays fp32 (reads fp32 xw).
// (b) conv LDS bank-conflict fix: activations stored as 16B slots indexed
// (kgroup*NPIX + pix) -> B-fragment reads are consecutive-slot = free
// 2-way (was 4/8-way at 32/64B pixel strides; 5.3e7 conflicts). Same
// plane sizes/offsets (pure slot permutation); weights packing unchanged.

typedef short short8 __attribute__((ext_vector_type(8)));
typedef float f32x4  __attribute__((ext_vector_type(4)));

__device__ __forceinline__ unsigned short f2bf(float f) {
    unsigned u = __builtin_bit_cast(unsigned, f);
    u = (u + 0x7FFFu + ((u >> 16) & 1u)) >> 16;
    return (unsigned short)u;
}
__device__ __forceinline__ float bf2f(unsigned short h) {
    unsigned u = ((unsigned)h) << 16;
    return __builtin_bit_cast(float, u);
}

// ---------------- LDS arena (bytes) ----------------------------------------
// L0out @0     : 10816 (169pix x 2kg x 16B, hi + lo at +5408)
// IN    @10816 : 7200  (225pix x 1kg x 16B, hi + lo at +3600)  dead after L0
// L1out @10816 : 15488 (121pix x 4kg x 16B, hi + lo at +7744)  overlaps IN
// L2out @0     : 5184  (81pix  x 2kg x 16B, hi + lo at +2592)  overlaps L0out
// ZED   @26304 : 16B of zeros (pad-lane B reads)
#define ZED_OFF 26304
#define ARENA_FLOATS 6592   // 26368 B

// ---------------------------------------------------------------------------
// Conv weight prep (UNCHANGED from R8): pack cw[l] into MFMA A-fragments,
// split-bf16. offset = ((c*NM + m)*2 + comp)*512 + lane*8 + j
// KIND 0 (L0):  c=ky;          kx=(lane>>4), ci=j; g==3 pad
// KIND 1 (L1/3):c=ky*2+half;   h0: kx=g>>1, ci=(g&1)*8+j
//                              h1: kx=2,    ci=(g&1)*8+j; g>=2 pad
// KIND 2 (L2):  c=ky*3+kx;     ci=g*8+j
// ---------------------------------------------------------------------------
__global__ __launch_bounds__(256) void wprep(
    const float* __restrict__ cw0, const float* __restrict__ cw1,
    const float* __restrict__ cw2, const float* __restrict__ cw3,
    short* __restrict__ wbuf)
{
    int gidx = blockIdx.x * 256 + threadIdx.x;
    if (gidx >= 36864) return;
    const float* cw; int base, CI, NM, KIND;
    if (gidx < 3072)       { cw = cw0; base = 0;     CI = 8;  NM = 1; KIND = 0; }
    else if (gidx < 15360) { cw = cw1; base = 3072;  CI = 16; NM = 2; KIND = 1; }
    else if (gidx < 24576) { cw = cw2; base = 15360; CI = 32; NM = 1; KIND = 2; }
    else                   { cw = cw3; base = 24576; CI = 16; NM = 2; KIND = 1; }
    int e = gidx - base;
    int j = e & 7, lane = (e >> 3) & 63, rest = e >> 9;
    int comp = rest & 1, cm = rest >> 1;
    int m = cm % NM, c = cm / NM;
    int g = lane >> 4, colr = lane & 15;
    int co = m * 16 + colr;
    int ky, kx, ci; bool pad = false;
    if (KIND == 0)      { ky = c; kx = g; ci = j; pad = (g >= 3); }
    else if (KIND == 1) {
        ky = c >> 1; int half = c & 1;
        if (half == 0) { kx = g >> 1; ci = (g & 1) * 8 + j; }
        else           { kx = 2;      ci = (g & 1) * 8 + j; pad = (g >= 2); }
    } else              { ky = c / 3; kx = c % 3; ci = g * 8 + j; }
    float w = pad ? 0.0f : cw[((co * CI + ci) * 3 + ky) * 3 + kx];
    unsigned short h = f2bf(w);
    wbuf[gidx] = (comp == 0) ? (short)h : (short)f2bf(w - bf2f(h));
}

// ---------------------------------------------------------------------------
// MLP weight prep: W[K][128] fp32 -> B-fragments hi/lo.
// wp[((kc*8 + nn)*2 + comp)*512 + lane*8 + j] = comp of
//   W[kc*32 + (lane>>4)*8 + j][nn*16 + (lane&15)]
// Layout: mw0 @0 (49 chunks, 401408), mw1 @401408, mw2 @434176, gw @466944.
// ---------------------------------------------------------------------------
__global__ __launch_bounds__(256) void wprep_mlp(
    const float* __restrict__ mw0, const float* __restrict__ mw1,
    const float* __restrict__ mw2, const float* __restrict__ gw,
    short* __restrict__ wp)
{
    int gidx = blockIdx.x * 256 + threadIdx.x;
    if (gidx >= 499712) return;
    const float* W; int base;
    if (gidx < 401408)      { W = mw0; base = 0; }
    else if (gidx < 434176) { W = mw1; base = 401408; }
    else if (gidx < 466944) { W = mw2; base = 434176; }
    else                    { W = gw;  base = 466944; }
    int e = gidx - base;
    int j = e & 7, lane = (e >> 3) & 63, rest = e >> 9;
    int comp = rest & 1, knn = rest >> 1;
    int nn = knn & 7, kc = knn >> 3;
    int k = kc * 32 + (lane >> 4) * 8 + j;
    int n = nn * 16 + (lane & 15);
    float w = W[(size_t)k * 128 + n];
    unsigned short h = f2bf(w);
    wp[gidx] = (comp == 0) ? (short)h : (short)f2bf(w - bf2f(h));
}

// ---------------------------------------------------------------------------
// One conv layer on MFMA, slot-layout LDS. Activation buffer at INOFF:
// addr(pix,kg,comp) = INOFF + comp*DIN + (kg*NPIN + pix)*16, slot shorts
// j=0..7 hold ci = kg*8+j. B-fragment read: 16 lanes = consecutive pix ->
// consecutive slots -> conflict-free. Per K=32 chunk: hh+lh+hl MFMAs.
// GOUT: write bf16 hi/lo planes to global (X0 for the MLP).
// ---------------------------------------------------------------------------
template<int CI, int CO, int WIN, int WOUT, int POUT, int NM, int NT,
         int KIND, int INOFF, int NPIN, int OUTOFF, int GOUT>
__device__ __forceinline__ void mfma_layer(
    float* __restrict__ A, const short* __restrict__ wbuf,
    const float* __restrict__ bias, short* __restrict__ gH,
    short* __restrict__ gL, int tid)
{
    const char* Ac = (const char*)A;
    char* Aw = (char*)A;
    const int wv = tid >> 6, lane = tid & 63;
    const int g = lane >> 4, col = lane & 15;
    constexpr int UNITS = NT * NM;
    constexpr int CPK = (KIND == 0) ? 1 : (KIND == 1) ? 2 : 3;
    constexpr int DIN = (CI / 8) * NPIN * 16;
    constexpr int DOUT = (CO / 8) * POUT * 16;
    const int u0 = (UNITS * wv) >> 2, u1 = (UNITS * (wv + 1)) >> 2;

#pragma unroll 1
    for (int u = u0; u < u1; ++u) {
        const int n = u / NM, m = u - n * NM;
        const int p = n * 16 + col;
        const bool valid = (p < POUT);
        const int pix = valid ? p : (POUT - 1);
        const int y = pix / WOUT;
        const int x = pix - y * WOUT;

        f32x4 acc;
        {
            const float4 bv = *(const float4*)(bias + m * 16 + g * 4);
            acc[0] = bv.x; acc[1] = bv.y; acc[2] = bv.z; acc[3] = bv.w;
        }

#pragma unroll
        for (int ky = 0; ky < 3; ++ky) {
#pragma unroll
            for (int cc = 0; cc < CPK; ++cc) {
                int kg, kx; bool okv;
                if (KIND == 0)      { kx = g;      kg = 0;     okv = (g < 3); }
                else if (KIND == 1) {
                    if (cc == 0)    { kx = g >> 1; kg = g & 1; okv = true; }
                    else            { kx = 2;      kg = g & 1; okv = (g < 2); }
                } else              { kx = cc;     kg = g;     okv = true; }
                const int pin = (y + ky) * WIN + x + kx;
                const int vH = okv ? (INOFF + (kg * NPIN + pin) * 16) : ZED_OFF;
                const int vL = okv ? (vH + DIN) : ZED_OFF;
                const int c = ky * CPK + cc;

                const short8 Ah = *(const short8*)(
                    wbuf + ((c * NM + m) * 2 + 0) * 512 + lane * 8);
                const short8 Al = *(const short8*)(
                    wbuf + ((c * NM + m) * 2 + 1) * 512 + lane * 8);

                const short8 Bh = *(const short8*)(Ac + vH);
                acc = __builtin_amdgcn_mfma_f32_16x16x32_bf16(Ah, Bh, acc, 0, 0, 0);
                acc = __builtin_amdgcn_mfma_f32_16x16x32_bf16(Al, Bh, acc, 0, 0, 0);
                const short8 Bl = *(const short8*)(Ac + vL);
                acc = __builtin_amdgcn_mfma_f32_16x16x32_bf16(Ah, Bl, acc, 0, 0, 0);
            }
        }

        if (GOUT) {
            if (valid) {
                const int co0 = m * 16 + g * 4;
#pragma unroll
                for (int r = 0; r < 4; ++r) {
                    float v = fmaxf(acc[r], 0.0f);
                    unsigned short h = f2bf(v);
                    gH[(co0 + r) * POUT + pix] = (short)h;
                    gL[(co0 + r) * POUT + pix] = (short)f2bf(v - bf2f(h));
                }
            }
        } else if (valid) {
            unsigned hh[2], ll[2];
#pragma unroll
            for (int r2 = 0; r2 < 2; ++r2) {
                float v0 = fmaxf(acc[r2 * 2 + 0], 0.0f);
                float v1 = fmaxf(acc[r2 * 2 + 1], 0.0f);
                unsigned short h0 = f2bf(v0), h1 = f2bf(v1);
                unsigned short l0 = f2bf(v0 - bf2f(h0));
                unsigned short l1 = f2bf(v1 - bf2f(h1));
                hh[r2] = (unsigned)h0 | ((unsigned)h1 << 16);
                ll[r2] = (unsigned)l0 | ((unsigned)l1 << 16);
            }
            const int kgO = m * 2 + (g >> 1);
            const int ob2 = OUTOFF + (kgO * POUT + pix) * 16 + (g & 1) * 8;
            *(uint2*)(Aw + ob2)        = make_uint2(hh[0], hh[1]);
            *(uint2*)(Aw + ob2 + DOUT) = make_uint2(ll[0], ll[1]);
        }
    }
}

__global__ __launch_bounds__(256) void conv_mfma(
    const float* __restrict__ states, const short* __restrict__ wbuf,
    const float* __restrict__ cb0, const float* __restrict__ cb1,
    const float* __restrict__ cb2, const float* __restrict__ cb3,
    short* __restrict__ x0h, short* __restrict__ x0l)
{
    __shared__ float A[ARENA_FLOATS];
    const int tid = threadIdx.x;

    if (tid < 4) A[ZED_OFF / 4 + tid] = 0.0f;

    // stage input: fp32 [8][15][15] -> slot layout bf16 hi/lo @10816
    const float* gin = states + (size_t)blockIdx.x * 1800;
    {
        char* Aw = (char*)A;
#pragma unroll
        for (int it = 0; it < 8; ++it) {
            int e = tid + it * 256;
            if (e < 1800) {
                float f = gin[e];
                int ci = e / 225, p = e - ci * 225;
                unsigned short h = f2bf(f);
                unsigned short l = f2bf(f - bf2f(h));
                int off = 10816 + p * 16 + ci * 2;
                *(short*)(Aw + off) = (short)h;
                *(short*)(Aw + off + 3600) = (short)l;
            }
        }
    }
    __syncthreads();

    // L0: 8->16, 15->13, in @10816 (225pix), out @0 (169pix)
    mfma_layer<8, 16, 15, 13, 169, 1, 11, 0, 10816, 225, 0, 0>(
        A, wbuf + 0, cb0, nullptr, nullptr, tid);
    __syncthreads();
    // L1: 16->32, 13->11, in @0 (169pix), out @10816 (121pix)
    mfma_layer<16, 32, 13, 11, 121, 2, 8, 1, 0, 169, 10816, 0>(
        A, wbuf + 3072, cb1, nullptr, nullptr, tid);
    __syncthreads();
    // L2: 32->16, 11->9, in @10816 (121pix), out @0 (81pix)
    mfma_layer<32, 16, 11, 9, 81, 1, 6, 2, 10816, 121, 0, 0>(
        A, wbuf + 15360, cb2, nullptr, nullptr, tid);
    __syncthreads();
    // L3: 16->32, 9->7, in @0 (81pix), out -> global bf16 hi/lo planes
    mfma_layer<16, 32, 9, 7, 49, 2, 4, 1, 0, 81, 0, 1>(
        A, wbuf + 24576, cb3,
        x0h + (size_t)blockIdx.x * 1568, x0l + (size_t)blockIdx.x * 1568, tid);
}

// ---------------------------------------------------------------------------
// MFMA GEMM: C[M x 128] = A[M x K] @ W[K x 128] (+bias)(+relu), split-bf16.
// A: hi/lo short planes [M][K]; W: packed fragments (wprep_mlp layout).
// Block = 64 rows (4 waves x 16), all 128 cols. 24 MFMA per K=32 chunk
// per wave. Output: bf16 hi/lo planes (chained GEMMs) or fp32 (xw).
// ---------------------------------------------------------------------------
template<int KCH, bool RELU, bool OUTF32>
__global__ __launch_bounds__(256) void mgemm(
    const short* __restrict__ Ah, const short* __restrict__ Al,
    const short* __restrict__ wp, const float* __restrict__ bias,
    short* __restrict__ Ch, short* __restrict__ Cl, float* __restrict__ Cf)
{
    constexpr int K = KCH * 32;
    const int tid = threadIdx.x;
    const int wv = tid >> 6, lane = tid & 63;
    const int col = lane & 15, g = lane >> 4;
    const int row0 = blockIdx.x * 64 + wv * 16;
    const size_t aoff = (size_t)(row0 + col) * K + g * 8;

    f32x4 acc[8];
#pragma unroll
    for (int nn = 0; nn < 8; ++nn) {
        float b = bias ? bias[nn * 16 + col] : 0.0f;
        acc[nn][0] = b; acc[nn][1] = b; acc[nn][2] = b; acc[nn][3] = b;
    }

#pragma unroll 2
    for (int kc = 0; kc < KCH; ++kc) {
        const short8 fAh = *(const short8*)(Ah + aoff + kc * 32);
        const short8 fAl = *(const short8*)(Al + aoff + kc * 32);
        const short* wk = wp + (size_t)kc * 8192 + lane * 8;
#pragma unroll
        for (int nn = 0; nn < 8; ++nn) {
            const short8 Bh = *(const short8*)(wk + (nn * 2 + 0) * 512);
            const short8 Bl = *(const short8*)(wk + (nn * 2 + 1) * 512);
            acc[nn] = __builtin_amdgcn_mfma_f32_16x16x32_bf16(fAh, Bh, acc[nn], 0, 0, 0);
            acc[nn] = __builtin_amdgcn_mfma_f32_16x16x32_bf16(fAl, Bh, acc[nn], 0, 0, 0);
            acc[nn] = __builtin_amdgcn_mfma_f32_16x16x32_bf16(fAh, Bl, acc[nn], 0, 0, 0);
        }
    }

#pragma unroll
    for (int nn = 0; nn < 8; ++nn) {
#pragma unroll
        for (int r = 0; r < 4; ++r) {
            float v = acc[nn][r];
            if (RELU) v = fmaxf(v, 0.0f);
            const size_t idx = (size_t)(row0 + g * 4 + r) * 128 + nn * 16 + col;
            if (OUTF32) {
                Cf[idx] = v;
            } else {
                unsigned short h = f2bf(v);
                Ch[idx] = (short)h;
                Cl[idx] = (short)f2bf(v - bf2f(h));
            }
        }
    }
}

// ---------------------------------------------------------------------------
// GCN aggregation: out[b,j] = dinv_j * sum_i (adj[b,i,j]*dinv_i*xw[b,i]) + gb
// ---------------------------------------------------------------------------
__global__ __launch_bounds__(256) void gcn_agg(
    const float* __restrict__ adj, const float* __restrict__ xw,
    const float* __restrict__ gb, float* __restrict__ outp)
{
    __shared__ float sAdj[64 * 64];
    __shared__ float sXW[64 * 128];
    __shared__ float sDinv[64];

    const int b = blockIdx.x;
    const int tid = threadIdx.x;

    const float* ga = adj + (size_t)b * 4096;
#pragma unroll
    for (int it = 0; it < 4; it++) {
        int idx = tid + it * 256;
        *(float4*)(sAdj + idx * 4) = *(const float4*)(ga + idx * 4);
    }
    const float* gx = xw + (size_t)b * 8192;
#pragma unroll
    for (int it = 0; it < 8; it++) {
        int idx = tid + it * 256;
        *(float4*)(sXW + idx * 4) = *(const float4*)(gx + idx * 4);
    }
    __syncthreads();

    if (tid < 64) {
        float d = 0.0f;
        for (int i = 0; i < 64; i++) d += sAdj[i * 64 + tid];
        sDinv[tid] = (d > 0.0f) ? rsqrtf(d) : 0.0f;
    }
    __syncthreads();

#pragma unroll
    for (int it = 0; it < 8; it++) {
        int idx = tid + it * 256;
        int i = idx >> 5;
        float s = sDinv[i];
        float4 v = *(float4*)(sXW + idx * 4);
        v.x *= s; v.y *= s; v.z *= s; v.w *= s;
        *(float4*)(sXW + idx * 4) = v;
    }
    __syncthreads();

    const int j  = tid >> 2;
    const int eb = (tid & 3) * 32;
    float acc[32];
#pragma unroll
    for (int e = 0; e < 32; e++) acc[e] = 0.0f;

    for (int i = 0; i < 64; i++) {
        float wgt = sAdj[i * 64 + j];
        const float* xp = sXW + i * 128 + eb;
#pragma unroll
        for (int e4 = 0; e4 < 8; e4++) {
            float4 v = *(const float4*)(xp + e4 * 4);
            acc[e4 * 4 + 0] += wgt * v.x;
            acc[e4 * 4 + 1] += wgt * v.y;
            acc[e4 * 4 + 2] += wgt * v.z;
            acc[e4 * 4 + 3] += wgt * v.w;
        }
    }

    const float dj = sDinv[j];
    float* go = outp + ((size_t)b * 64 + j) * 128 + eb;
#pragma unroll
    for (int e4 = 0; e4 < 8; e4++) {
        float4 v;
        v.x = acc[e4 * 4 + 0] * dj + gb[eb + e4 * 4 + 0];
        v.y = acc[e4 * 4 + 1] * dj + gb[eb + e4 * 4 + 1];
        v.z = acc[e4 * 4 + 2] * dj + gb[eb + e4 * 4 + 2];
        v.w = acc[e4 * 4 + 3] * dj + gb[eb + e4 * 4 + 3];
        *(float4*)(go + e4 * 4) = v;
    }
}

// ---------------------------------------------------------------------------
extern "C" void kernel_launch(void* const* d_in, const int* in_sizes, int n_in,
                              void* d_out, int out_size, void* d_ws, size_t ws_size,
                              hipStream_t stream)
{
    const float* states = (const float*)d_in[0];
    const float* adj    = (const float*)d_in[1];
    const float* cw0 = (const float*)d_in[2];  const float* cb0 = (const float*)d_in[3];
    const float* cw1 = (const float*)d_in[4];  const float* cb1 = (const float*)d_in[5];
    const float* cw2 = (const float*)d_in[6];  const float* cb2 = (const float*)d_in[7];
    const float* cw3 = (const float*)d_in[8];  const float* cb3 = (const float*)d_in[9];
    const float* mw0 = (const float*)d_in[10]; const float* mb0 = (const float*)d_in[11];
    const float* mw1 = (const float*)d_in[12]; const float* mb1 = (const float*)d_in[13];
    const float* mw2 = (const float*)d_in[14]; const float* mb2 = (const float*)d_in[15];
    const float* gw  = (const float*)d_in[16]; const float* gb  = (const float*)d_in[17];

    float* ws = (float*)d_ws;
    const size_t X0E = (size_t)16384 * 1568;          // 25,690,112

    // X0 region (same 102.8MB footprint as old fp32 X0): hi/lo planes
    short* X0h = (short*)ws;
    short* X0l = X0h + X0E;
    // Bu region: H1 hi/lo
    short* H1h = (short*)(ws + X0E);
    short* H1l = H1h + 2097152;
    // Cu region: H2 hi/lo
    short* H2h = (short*)(ws + X0E + 2097152);
    short* H2l = H2h + 2097152;
    // packed weights after Cu
    short* WBc = (short*)(ws + X0E + 2 * 2097152);    // 36,864 shorts
    short* WPm = WBc + 36864;                         // 499,712 shorts
    // feats + xw alias the (dead-by-then) X0 region
    short* Fh = (short*)ws;                           // 2,097,152 shorts
    short* Fl = Fh + 2097152;
    float* xw = ws + 2097152;                         // fp32, past F planes

    float* out = (float*)d_out;

    wprep<<<144, 256, 0, stream>>>(cw0, cw1, cw2, cw3, WBc);
    wprep_mlp<<<1952, 256, 0, stream>>>(mw0, mw1, mw2, gw, WPm);
    conv_mfma<<<16384, 256, 0, stream>>>(states, WBc, cb0, cb1, cb2, cb3,
                                         X0h, X0l);
    mgemm<49, true,  false><<<256, 256, 0, stream>>>(X0h, X0l, WPm + 0,
                                                     mb0, H1h, H1l, nullptr);
    mgemm<4,  true,  false><<<256, 256, 0, stream>>>(H1h, H1l, WPm + 401408,
                                                     mb1, H2h, H2l, nullptr);
    mgemm<4,  false, false><<<256, 256, 0, stream>>>(H2h, H2l, WPm + 434176,
                                                     mb2, Fh, Fl, nullptr);
    mgemm<4,  false, true ><<<256, 256, 0, stream>>>(Fh, Fl, WPm + 466944,
                                                     nullptr, nullptr, nullptr, xw);
    gcn_agg<<<256, 256, 0, stream>>>(adj, xw, gb, out);
}

// Round 10
// 563.580 us; speedup vs baseline: 1.1998x; 1.1998x over previous
//
#include <hip/hip_runtime.h>

// MultiGNN: B=256, A=64 -> 16384 images of 8x15x15
// convs: 8->16 (15->13), 16->32 (13->11), 32->16 (11->9), 16->32 (9->7)
// flatten 32*7*7=1568 -> MLP 128,128,128 -> GCN over 64 agents, E=128
//
// R10: fuse the whole tail. R9 showed the tail (342us) is launch/latency/
// memory-pass bound, not FLOP bound (MFMA-izing the GEMMs changed nothing).
// A 64-row MLP block == one graph, so H1->H2->feats->xw->GCN becomes ONE
// kernel (mlp_gcn, 256 blocks): X0 staged coalesced into LDS per 128-k
// superstep, stage outputs chained through LDS in MFMA fragment layout,
// GCN aggregation on the in-LDS XW. Intermediates never touch HBM;
// launches 8 -> 3. Conv kernel byte-identical to R9 (334us).

typedef short short8 __attribute__((ext_vector_type(8)));
typedef float f32x4  __attribute__((ext_vector_type(4)));

__device__ __forceinline__ unsigned short f2bf(float f) {
    unsigned u = __builtin_bit_cast(unsigned, f);
    u = (u + 0x7FFFu + ((u >> 16) & 1u)) >> 16;
    return (unsigned short)u;
}
__device__ __forceinline__ float bf2f(unsigned short h) {
    unsigned u = ((unsigned)h) << 16;
    return __builtin_bit_cast(float, u);
}

// ---------------- conv LDS arena (bytes) -----------------------------------
// L0out @0     : 10816 (169pix x 2kg x 16B, hi + lo at +5408)
// IN    @10816 : 7200  (225pix x 1kg x 16B, hi + lo at +3600)  dead after L0
// L1out @10816 : 15488 (121pix x 4kg x 16B, hi + lo at +7744)  overlaps IN
// L2out @0     : 5184  (81pix  x 2kg x 16B, hi + lo at +2592)  overlaps L0out
// ZED   @26304 : 16B of zeros (pad-lane B reads)
#define ZED_OFF 26304
#define ARENA_FLOATS 6592   // 26368 B

// ---------------------------------------------------------------------------
// Combined weight prep.
// gidx < 36864: conv weights (R9 layout, unchanged):
//   offset = ((c*NM + m)*2 + comp)*512 + lane*8 + j
//   KIND 0 (L0):  c=ky;          kx=(lane>>4), ci=j; g==3 pad
//   KIND 1 (L1/3):c=ky*2+half;   h0: kx=g>>1, ci=(g&1)*8+j
//                                h1: kx=2,    ci=(g&1)*8+j; g>=2 pad
//   KIND 2 (L2):  c=ky*3+kx;     ci=g*8+j
// else: MLP/GCN weights W[K][128] -> B-fragments hi/lo:
//   wp[((kc*8 + nn)*2 + comp)*512 + lane*8 + j] =
//     comp of W[kc*32 + (lane>>4)*8 + j][nn*16 + (lane&15)]
//   mw0 @0 (49 chunks), mw1 @401408, mw2 @434176, gw @466944.
// ---------------------------------------------------------------------------
__global__ __launch_bounds__(256) void wprep_all(
    const float* __restrict__ cw0, const float* __restrict__ cw1,
    const float* __restrict__ cw2, const float* __restrict__ cw3,
    const float* __restrict__ mw0, const float* __restrict__ mw1,
    const float* __restrict__ mw2, const float* __restrict__ gw,
    short* __restrict__ wbuf, short* __restrict__ wp)
{
    int gidx = blockIdx.x * 256 + threadIdx.x;
    if (gidx < 36864) {
        const float* cw; int base, CI, NM, KIND;
        if (gidx < 3072)       { cw = cw0; base = 0;     CI = 8;  NM = 1; KIND = 0; }
        else if (gidx < 15360) { cw = cw1; base = 3072;  CI = 16; NM = 2; KIND = 1; }
        else if (gidx < 24576) { cw = cw2; base = 15360; CI = 32; NM = 1; KIND = 2; }
        else                   { cw = cw3; base = 24576; CI = 16; NM = 2; KIND = 1; }
        int e = gidx - base;
        int j = e & 7, lane = (e >> 3) & 63, rest = e >> 9;
        int comp = rest & 1, cm = rest >> 1;
        int m = cm % NM, c = cm / NM;
        int g = lane >> 4, colr = lane & 15;
        int co = m * 16 + colr;
        int ky, kx, ci; bool pad = false;
        if (KIND == 0)      { ky = c; kx = g; ci = j; pad = (g >= 3); }
        else if (KIND == 1) {
            ky = c >> 1; int half = c & 1;
            if (half == 0) { kx = g >> 1; ci = (g & 1) * 8 + j; }
            else           { kx = 2;      ci = (g & 1) * 8 + j; pad = (g >= 2); }
        } else              { ky = c / 3; kx = c % 3; ci = g * 8 + j; }
        float w = pad ? 0.0f : cw[((co * CI + ci) * 3 + ky) * 3 + kx];
        unsigned short h = f2bf(w);
        wbuf[gidx] = (comp == 0) ? (short)h : (short)f2bf(w - bf2f(h));
    } else {
        int e0 = gidx - 36864;
        if (e0 >= 499712) return;
        const float* W; int base;
        if (e0 < 401408)      { W = mw0; base = 0; }
        else if (e0 < 434176) { W = mw1; base = 401408; }
        else if (e0 < 466944) { W = mw2; base = 434176; }
        else                  { W = gw;  base = 466944; }
        int e = e0 - base;
        int j = e & 7, lane = (e >> 3) & 63, rest = e >> 9;
        int comp = rest & 1, knn = rest >> 1;
        int nn = knn & 7, kc = knn >> 3;
        int k = kc * 32 + (lane >> 4) * 8 + j;
        int n = nn * 16 + (lane & 15);
        float w = W[(size_t)k * 128 + n];
        unsigned short h = f2bf(w);
        wp[e0] = (comp == 0) ? (short)h : (short)f2bf(w - bf2f(h));
    }
}

// ---------------------------------------------------------------------------
// One conv layer on MFMA (UNCHANGED from R9). Slot layout LDS:
// addr(pix,kg,comp) = INOFF + comp*DIN + (kg*NPIN + pix)*16.
// ---------------------------------------------------------------------------
template<int CI, int CO, int WIN, int WOUT, int POUT, int NM, int NT,
         int KIND, int INOFF, int NPIN, int OUTOFF, int GOUT>
__device__ __forceinline__ void mfma_layer(
    float* __restrict__ A, const short* __restrict__ wbuf,
    const float* __restrict__ bias, short* __restrict__ gH,
    short* __restrict__ gL, int tid)
{
    const char* Ac = (const char*)A;
    char* Aw = (char*)A;
    const int wv = tid >> 6, lane = tid & 63;
    const int g = lane >> 4, col = lane & 15;
    constexpr int UNITS = NT * NM;
    constexpr int CPK = (KIND == 0) ? 1 : (KIND == 1) ? 2 : 3;
    constexpr int DIN = (CI / 8) * NPIN * 16;
    constexpr int DOUT = (CO / 8) * POUT * 16;
    const int u0 = (UNITS * wv) >> 2, u1 = (UNITS * (wv + 1)) >> 2;

#pragma unroll 1
    for (int u = u0; u < u1; ++u) {
        const int n = u / NM, m = u - n * NM;
        const int p = n * 16 + col;
        const bool valid = (p < POUT);
        const int pix = valid ? p : (POUT - 1);
        const int y = pix / WOUT;
        const int x = pix - y * WOUT;

        f32x4 acc;
        {
            const float4 bv = *(const float4*)(bias + m * 16 + g * 4);
            acc[0] = bv.x; acc[1] = bv.y; acc[2] = bv.z; acc[3] = bv.w;
        }

#pragma unroll
        for (int ky = 0; ky < 3; ++ky) {
#pragma unroll
            for (int cc = 0; cc < CPK; ++cc) {
                int kg, kx; bool okv;
                if (KIND == 0)      { kx = g;      kg = 0;     okv = (g < 3); }
                else if (KIND == 1) {
                    if (cc == 0)    { kx = g >> 1; kg = g & 1; okv = true; }
                    else            { kx = 2;      kg = g & 1; okv = (g < 2); }
                } else              { kx = cc;     kg = g;     okv = true; }
                const int pin = (y + ky) * WIN + x + kx;
                const int vH = okv ? (INOFF + (kg * NPIN + pin) * 16) : ZED_OFF;
                const int vL = okv ? (vH + DIN) : ZED_OFF;
                const int c = ky * CPK + cc;

                const short8 Ah = *(const short8*)(
                    wbuf + ((c * NM + m) * 2 + 0) * 512 + lane * 8);
                const short8 Al = *(const short8*)(
                    wbuf + ((c * NM + m) * 2 + 1) * 512 + lane * 8);

                const short8 Bh = *(const short8*)(Ac + vH);
                acc = __builtin_amdgcn_mfma_f32_16x16x32_bf16(Ah, Bh, acc, 0, 0, 0);
                acc = __builtin_amdgcn_mfma_f32_16x16x32_bf16(Al, Bh, acc, 0, 0, 0);
                const short8 Bl = *(const short8*)(Ac + vL);
                acc = __builtin_amdgcn_mfma_f32_16x16x32_bf16(Ah, Bl, acc, 0, 0, 0);
            }
        }

        if (GOUT) {
            if (valid) {
                const int co0 = m * 16 + g * 4;
#pragma unroll
                for (int r = 0; r < 4; ++r) {
                    float v = fmaxf(acc[r], 0.0f);
                    unsigned short h = f2bf(v);
                    gH[(co0 + r) * POUT + pix] = (short)h;
                    gL[(co0 + r) * POUT + pix] = (short)f2bf(v - bf2f(h));
                }
            }
        } else if (valid) {
            unsigned hh[2], ll[2];
#pragma unroll
            for (int r2 = 0; r2 < 2; ++r2) {
                float v0 = fmaxf(acc[r2 * 2 + 0], 0.0f);
                float v1 = fmaxf(acc[r2 * 2 + 1], 0.0f);
                unsigned short h0 = f2bf(v0), h1 = f2bf(v1);
                unsigned short l0 = f2bf(v0 - bf2f(h0));
                unsigned short l1 = f2bf(v1 - bf2f(h1));
                hh[r2] = (unsigned)h0 | ((unsigned)h1 << 16);
                ll[r2] = (unsigned)l0 | ((unsigned)l1 << 16);
            }
            const int kgO = m * 2 + (g >> 1);
            const int ob2 = OUTOFF + (kgO * POUT + pix) * 16 + (g & 1) * 8;
            *(uint2*)(Aw + ob2)        = make_uint2(hh[0], hh[1]);
            *(uint2*)(Aw + ob2 + DOUT) = make_uint2(ll[0], ll[1]);
        }
    }
}

__global__ __launch_bounds__(256) void conv_mfma(
    const float* __restrict__ states, const short* __restrict__ wbuf,
    const float* __restrict__ cb0, const float* __restrict__ cb1,
    const float* __restrict__ cb2, const float* __restrict__ cb3,
    short* __restrict__ x0h, short* __restrict__ x0l)
{
    __shared__ float A[ARENA_FLOATS];
    const int tid = threadIdx.x;

    if (tid < 4) A[ZED_OFF / 4 + tid] = 0.0f;

    const float* gin = states + (size_t)blockIdx.x * 1800;
    {
        char* Aw = (char*)A;
#pragma unroll
        for (int it = 0; it < 8; ++it) {
            int e = tid + it * 256;
            if (e < 1800) {
                float f = gin[e];
                int ci = e / 225, p = e - ci * 225;
                unsigned short h = f2bf(f);
                unsigned short l = f2bf(f - bf2f(h));
                int off = 10816 + p * 16 + ci * 2;
                *(short*)(Aw + off) = (short)h;
                *(short*)(Aw + off + 3600) = (short)l;
            }
        }
    }
    __syncthreads();

    mfma_layer<8, 16, 15, 13, 169, 1, 11, 0, 10816, 225, 0, 0>(
        A, wbuf + 0, cb0, nullptr, nullptr, tid);
    __syncthreads();
    mfma_layer<16, 32, 13, 11, 121, 2, 8, 1, 0, 169, 10816, 0>(
        A, wbuf + 3072, cb1, nullptr, nullptr, tid);
    __syncthreads();
    mfma_layer<32, 16, 11, 9, 81, 1, 6, 2, 10816, 121, 0, 0>(
        A, wbuf + 15360, cb2, nullptr, nullptr, tid);
    __syncthreads();
    mfma_layer<16, 32, 9, 7, 49, 2, 4, 1, 0, 81, 0, 1>(
        A, wbuf + 24576, cb3,
        x0h + (size_t)blockIdx.x * 1568, x0l + (size_t)blockIdx.x * 1568, tid);
}

// ---------------------------------------------------------------------------
// Fused MLP + GCN. One block = 64 rows = one graph b.
// H1: 12 supersteps of 128k (X0 staged coalesced to SA, stride 132) + 32k
// tail; acc over all chunks. Chain H2/F/XW through LDS (stage result
// written in row-major fragment-readable layout, relu+split-bf16).
// XW -> sXW fp32, then GCN aggregation (proven gcn_agg code) -> out.
// Each wave owns rows [wv*16, wv*16+16); fragment reads only touch own rows.
// ---------------------------------------------------------------------------
__global__ __launch_bounds__(256) void mlp_gcn(
    const short* __restrict__ X0h, const short* __restrict__ X0l,
    const short* __restrict__ wp,
    const float* __restrict__ mb0, const float* __restrict__ mb1,
    const float* __restrict__ mb2, const float* __restrict__ adj,
    const float* __restrict__ gb, float* __restrict__ outp)
{
    __shared__ short SAh[64 * 132], SAl[64 * 132];
    __shared__ short SBh[64 * 132], SBl[64 * 132];
    __shared__ float sXW[64 * 128];
    __shared__ float sAdj[64 * 64];
    __shared__ float sDinv[64];

    const int b = blockIdx.x;
    const int tid = threadIdx.x;
    const int wv = tid >> 6, lane = tid & 63;
    const int col = lane & 15, g = lane >> 4;
    const int wr0 = wv * 16;
    const size_t grow = (size_t)b * 64;

    // adj prefetch (consumed after XW; barriers in between order it)
    {
        const float* ga = adj + (size_t)b * 4096;
#pragma unroll
        for (int it = 0; it < 4; ++it) {
            int idx = tid + it * 256;
            *(float4*)(sAdj + idx * 4) = *(const float4*)(ga + idx * 4);
        }
    }

    f32x4 acc[8];
#pragma unroll
    for (int nn = 0; nn < 8; ++nn) {
        float bv = mb0[nn * 16 + col];
        acc[nn][0] = bv; acc[nn][1] = bv; acc[nn][2] = bv; acc[nn][3] = bv;
    }

    // ---- H1: 12 full supersteps (128 k each) ----
#pragma unroll 1
    for (int ss = 0; ss < 12; ++ss) {
        const int kbase = ss * 128;
        __syncthreads();   // protect SA from previous superstep's readers
#pragma unroll
        for (int it = 0; it < 4; ++it) {
            int v = tid + it * 256;           // 1024 vec16 slots = 64 rows x 16
            int row = v >> 4, u = v & 15;
            size_t gofs = (grow + row) * 1568 + kbase + u * 8;
            *(short8*)(SAh + row * 132 + u * 8) = *(const short8*)(X0h + gofs);
            *(short8*)(SAl + row * 132 + u * 8) = *(const short8*)(X0l + gofs);
        }
        __syncthreads();
#pragma unroll
        for (int kc = 0; kc < 4; ++kc) {
            const short8 fAh = *(const short8*)(SAh + (wr0 + col) * 132 + kc * 32 + g * 8);
            const short8 fAl = *(const short8*)(SAl + (wr0 + col) * 132 + kc * 32 + g * 8);
            const short* wk = wp + (size_t)(ss * 4 + kc) * 8192 + lane * 8;
#pragma unroll
            for (int nn = 0; nn < 8; ++nn) {
                const short8 Bh = *(const short8*)(wk + (nn * 2 + 0) * 512);
                const short8 Bl = *(const short8*)(wk + (nn * 2 + 1) * 512);
                acc[nn] = __builtin_amdgcn_mfma_f32_16x16x32_bf16(fAh, Bh, acc[nn], 0, 0, 0);
                acc[nn] = __builtin_amdgcn_mfma_f32_16x16x32_bf16(fAl, Bh, acc[nn], 0, 0, 0);
                acc[nn] = __builtin_amdgcn_mfma_f32_16x16x32_bf16(fAh, Bl, acc[nn], 0, 0, 0);
            }
        }
    }
    // ---- H1 tail: k = 1536..1567 (chunk 48) ----
    __syncthreads();
    {
        int row = tid >> 2, u = tid & 3;      // 256 threads = 64 rows x 4
        size_t gofs = (grow + row) * 1568 + 1536 + u * 8;
        *(short8*)(SAh + row * 132 + u * 8) = *(const short8*)(X0h + gofs);
        *(short8*)(SAl + row * 132 + u * 8) = *(const short8*)(X0l + gofs);
    }
    __syncthreads();
    {
        const short8 fAh = *(const short8*)(SAh + (wr0 + col) * 132 + g * 8);
        const short8 fAl = *(const short8*)(SAl + (wr0 + col) * 132 + g * 8);
        const short* wk = wp + (size_t)48 * 8192 + lane * 8;
#pragma unroll
        for (int nn = 0; nn < 8; ++nn) {
            const short8 Bh = *(const short8*)(wk + (nn * 2 + 0) * 512);
            const short8 Bl = *(const short8*)(wk + (nn * 2 + 1) * 512);
            acc[nn] = __builtin_amdgcn_mfma_f32_16x16x32_bf16(fAh, Bh, acc[nn], 0, 0, 0);
            acc[nn] = __builtin_amdgcn_mfma_f32_16x16x32_bf16(fAl, Bh, acc[nn], 0, 0, 0);
            acc[nn] = __builtin_amdgcn_mfma_f32_16x16x32_bf16(fAh, Bl, acc[nn], 0, 0, 0);
        }
    }
    __syncthreads();
    // H1 result -> SB (relu + split)
#pragma unroll
    for (int nn = 0; nn < 8; ++nn)
#pragma unroll
        for (int r = 0; r < 4; ++r) {
            float v = fmaxf(acc[nn][r], 0.0f);
            unsigned short h = f2bf(v);
            int row = wr0 + g * 4 + r;
            SBh[row * 132 + nn * 16 + col] = (short)h;
            SBl[row * 132 + nn * 16 + col] = (short)f2bf(v - bf2f(h));
        }
    __syncthreads();

    // ---- H2: SB -> SA (relu) ----
#pragma unroll
    for (int nn = 0; nn < 8; ++nn) {
        float bv = mb1[nn * 16 + col];
        acc[nn][0] = bv; acc[nn][1] = bv; acc[nn][2] = bv; acc[nn][3] = bv;
    }
#pragma unroll
    for (int kc = 0; kc < 4; ++kc) {
        const short8 fAh = *(const short8*)(SBh + (wr0 + col) * 132 + kc * 32 + g * 8);
        const short8 fAl = *(const short8*)(SBl + (wr0 + col) * 132 + kc * 32 + g * 8);
        const short* wk = wp + 401408 + (size_t)kc * 8192 + lane * 8;
#pragma unroll
        for (int nn = 0; nn < 8; ++nn) {
            const short8 Bh = *(const short8*)(wk + (nn * 2 + 0) * 512);
            const short8 Bl = *(const short8*)(wk + (nn * 2 + 1) * 512);
            acc[nn] = __builtin_amdgcn_mfma_f32_16x16x32_bf16(fAh, Bh, acc[nn], 0, 0, 0);
            acc[nn] = __builtin_amdgcn_mfma_f32_16x16x32_bf16(fAl, Bh, acc[nn], 0, 0, 0);
            acc[nn] = __builtin_amdgcn_mfma_f32_16x16x32_bf16(fAh, Bl, acc[nn], 0, 0, 0);
        }
    }
#pragma unroll
    for (int nn = 0; nn < 8; ++nn)
#pragma unroll
        for (int r = 0; r < 4; ++r) {
            float v = fmaxf(acc[nn][r], 0.0f);
            unsigned short h = f2bf(v);
            int row = wr0 + g * 4 + r;
            SAh[row * 132 + nn * 16 + col] = (short)h;
            SAl[row * 132 + nn * 16 + col] = (short)f2bf(v - bf2f(h));
        }
    __syncthreads();

    // ---- feats: SA -> SB (no relu) ----
#pragma unroll
    for (int nn = 0; nn < 8; ++nn) {
        float bv = mb2[nn * 16 + col];
        acc[nn][0] = bv; acc[nn][1] = bv; acc[nn][2] = bv; acc[nn][3] = bv;
    }
#pragma unroll
    for (int kc = 0; kc < 4; ++kc) {
        const short8 fAh = *(const short8*)(SAh + (wr0 + col) * 132 + kc * 32 + g * 8);
        const short8 fAl = *(const short8*)(SAl + (wr0 + col) * 132 + kc * 32 + g * 8);
        const short* wk = wp + 434176 + (size_t)kc * 8192 + lane * 8;
#pragma unroll
        for (int nn = 0; nn < 8; ++nn) {
            const short8 Bh = *(const short8*)(wk + (nn * 2 + 0) * 512);
            const short8 Bl = *(const short8*)(wk + (nn * 2 + 1) * 512);
            acc[nn] = __builtin_amdgcn_mfma_f32_16x16x32_bf16(fAh, Bh, acc[nn], 0, 0, 0);
            acc[nn] = __builtin_amdgcn_mfma_f32_16x16x32_bf16(fAl, Bh, acc[nn], 0, 0, 0);
            acc[nn] = __builtin_amdgcn_mfma_f32_16x16x32_bf16(fAh, Bl, acc[nn], 0, 0, 0);
        }
    }
#pragma unroll
    for (int nn = 0; nn < 8; ++nn)
#pragma unroll
        for (int r = 0; r < 4; ++r) {
            float v = acc[nn][r];
            unsigned short h = f2bf(v);
            int row = wr0 + g * 4 + r;
            SBh[row * 132 + nn * 16 + col] = (short)h;
            SBl[row * 132 + nn * 16 + col] = (short)f2bf(v - bf2f(h));
        }
    __syncthreads();

    // ---- xw: SB -> sXW (fp32, no bias) ----
#pragma unroll
    for (int nn = 0; nn < 8; ++nn) {
        acc[nn][0] = 0.0f; acc[nn][1] = 0.0f; acc[nn][2] = 0.0f; acc[nn][3] = 0.0f;
    }
#pragma unroll
    for (int kc = 0; kc < 4; ++kc) {
        const short8 fAh = *(const short8*)(SBh + (wr0 + col) * 132 + kc * 32 + g * 8);
        const short8 fAl = *(const short8*)(SBl + (wr0 + col) * 132 + kc * 32 + g * 8);
        const short* wk = wp + 466944 + (size_t)kc * 8192 + lane * 8;
#pragma unroll
        for (int nn = 0; nn < 8; ++nn) {
            const short8 Bh = *(const short8*)(wk + (nn * 2 + 0) * 512);
            const short8 Bl = *(const short8*)(wk + (nn * 2 + 1) * 512);
            acc[nn] = __builtin_amdgcn_mfma_f32_16x16x32_bf16(fAh, Bh, acc[nn], 0, 0, 0);
            acc[nn] = __builtin_amdgcn_mfma_f32_16x16x32_bf16(fAl, Bh, acc[nn], 0, 0, 0);
            acc[nn] = __builtin_amdgcn_mfma_f32_16x16x32_bf16(fAh, Bl, acc[nn], 0, 0, 0);
        }
    }
#pragma unroll
    for (int nn = 0; nn < 8; ++nn)
#pragma unroll
        for (int r = 0; r < 4; ++r)
            sXW[(wr0 + g * 4 + r) * 128 + nn * 16 + col] = acc[nn][r];
    __syncthreads();

    // ---- GCN aggregation (gcn_agg body, sXW/sAdj in LDS) ----
    if (tid < 64) {
        float d = 0.0f;
        for (int i = 0; i < 64; i++) d += sAdj[i * 64 + tid];
        sDinv[tid] = (d > 0.0f) ? rsqrtf(d) : 0.0f;
    }
    __syncthreads();

#pragma unroll
    for (int it = 0; it < 8; it++) {
        int idx = tid + it * 256;
        int i = idx >> 5;
        float s = sDinv[i];
        float4 v = *(float4*)(sXW + idx * 4);
        v.x *= s; v.y *= s; v.z *= s; v.w *= s;
        *(float4*)(sXW + idx * 4) = v;
    }
    __syncthreads();

    const int j  = tid >> 2;
    const int eb = (tid & 3) * 32;
    float ac[32];
#pragma unroll
    for (int e = 0; e < 32; e++) ac[e] = 0.0f;

    for (int i = 0; i < 64; i++) {
        float wgt = sAdj[i * 64 + j];
        const float* xp = sXW + i * 128 + eb;
#pragma unroll
        for (int e4 = 0; e4 < 8; e4++) {
            float4 v = *(const float4*)(xp + e4 * 4);
            ac[e4 * 4 + 0] += wgt * v.x;
            ac[e4 * 4 + 1] += wgt * v.y;
            ac[e4 * 4 + 2] += wgt * v.z;
            ac[e4 * 4 + 3] += wgt * v.w;
        }
    }

    const float dj = sDinv[j];
    float* go = outp + ((size_t)b * 64 + j) * 128 + eb;
#pragma unroll
    for (int e4 = 0; e4 < 8; e4++) {
        float4 v;
        v.x = ac[e4 * 4 + 0] * dj + gb[eb + e4 * 4 + 0];
        v.y = ac[e4 * 4 + 1] * dj + gb[eb + e4 * 4 + 1];
        v.z = ac[e4 * 4 + 2] * dj + gb[eb + e4 * 4 + 2];
        v.w = ac[e4 * 4 + 3] * dj + gb[eb + e4 * 4 + 3];
        *(float4*)(go + e4 * 4) = v;
    }
}

// ---------------------------------------------------------------------------
extern "C" void kernel_launch(void* const* d_in, const int* in_sizes, int n_in,
                              void* d_out, int out_size, void* d_ws, size_t ws_size,
                              hipStream_t stream)
{
    const float* states = (const float*)d_in[0];
    const float* adj    = (const float*)d_in[1];
    const float* cw0 = (const float*)d_in[2];  const float* cb0 = (const float*)d_in[3];
    const float* cw1 = (const float*)d_in[4];  const float* cb1 = (const float*)d_in[5];
    const float* cw2 = (const float*)d_in[6];  const float* cb2 = (const float*)d_in[7];
    const float* cw3 = (const float*)d_in[8];  const float* cb3 = (const float*)d_in[9];
    const float* mw0 = (const float*)d_in[10]; const float* mb0 = (const float*)d_in[11];
    const float* mw1 = (const float*)d_in[12]; const float* mb1 = (const float*)d_in[13];
    const float* mw2 = (const float*)d_in[14]; const float* mb2 = (const float*)d_in[15];
    const float* gw  = (const float*)d_in[16]; const float* gb  = (const float*)d_in[17];

    const size_t X0E = (size_t)16384 * 1568;   // 25,690,112 shorts per plane
    short* X0h = (short*)d_ws;
    short* X0l = X0h + X0E;
    short* WBc = X0l + X0E;                    // 36,864 shorts (conv packed)
    short* WPm = WBc + 36864;                  // 499,712 shorts (mlp packed)

    float* out = (float*)d_out;

    wprep_all<<<2096, 256, 0, stream>>>(cw0, cw1, cw2, cw3,
                                        mw0, mw1, mw2, gw, WBc, WPm);
    conv_mfma<<<16384, 256, 0, stream>>>(states, WBc, cb0, cb1, cb2, cb3,
                                         X0h, X0l);
    mlp_gcn<<<256, 256, 0, stream>>>(X0h, X0l, WPm, mb0, mb1, mb2,
                                     adj, gb, out);
}